// Round 14
// baseline (75.342 us; speedup 1.0000x reference)
//
#include <hip/hip_runtime.h>

// ColorHistogramLoss: soft histogram (Gaussian kernel, 64 bins) over
// pred/target (4,3,256,256) fp32, normalized, cumsum, mean |cdf diff|.
//
// v13: MEASUREMENT PROBE #2 — v11 verbatim, final_kernel launched 4x
//   (idempotent: reads unchanged partials, rewrites same out[0]).
//   (total − 64.4)/3 = final_dur + one dispatch boundary, with 3x noise
//   amplification. Completes the ledger decomposition started by v12
//   (which measured hist + boundary = 5.2us -> hist ~4us, issue-bound
//   model confirmed; hist is done).
//   Pre-committed: total <= ~74 -> final+bnd <= 3us -> residual ~14us is
//   fixed harness overhead -> declare roofline next round.
//   total >= ~90 -> final+bnd >= 8.5us -> optimize final next round.
//
//   Session ledger (best = 64.4us, v6/v11):
//   - fill (harness d_ws poison): 41us @ 82% HBM peak — untouchable.
//   - hist + boundary: 5.2us (v12 probe) — at LDS-issue floor.
//   - LDS atomicAdd ~200cy/op contention-independent (v2/v3) -> plain RMW.
//   - Row-major h[wave][bin][lane]: bank=lane%32 data-independent free;
//     transposed/b64 (v5): data-dependent clumping, regressed.
//   - 4 blk/CU (v8), grid.sync (v7), fence-storm (v9), RMW-poll (v10):
//     all regressed.
//
// Structure:
//   hist_kernel    : 768 blocks x 128 thr (3 blocks/CU)
//   final_kernel x4: 1 block x 768 thr (PROBE — revert to x1 after)

#define BINS 64
#define NCH 12            // B*C = 4*3
#define HW 65536          // 256*256
#define BPC 32            // pixel-chunks (blocks) per channel-image
#define PIX_PER_BLOCK (HW / BPC)              // 2048
#define THREADS 128
#define PPT (PIX_PER_BLOCK / THREADS)         // 16 pixels per thread
#define R 4               // Gaussian support radius (edge weight e^-8)
#define WIN (2 * R + 1)   // 9 taps
#define PADBINS (BINS + 2 * R)   // 72 rows: row = bin + R, bins -4..67
#define NW (THREADS / 64) // 2 waves

__device__ __forceinline__ float fast_exp2(float x) {
#if __has_builtin(__builtin_amdgcn_exp2f)
    return __builtin_amdgcn_exp2f(x);   // v_exp_f32
#else
    return exp2f(x);
#endif
}

// weight for bin i-R+t (t=0..8): exp(-(f-(t-R))^2/2) = CK[t] * P_t,
//   P_0 = exp(-f^2/2 - R*f)  (one exp2)    B = exp(f)  (one exp2)
//   P_{t+1} = P_t * B ;  CK[t] = exp(-(t-R)^2/2)  (compile-time)
__global__ __launch_bounds__(THREADS) void hist_kernel(
        const float* __restrict__ pred,
        const float* __restrict__ target,
        float* __restrict__ part_out) {
    constexpr float CK[WIN] = {
        3.3546262790251185e-04f, 1.1108996538242306e-02f,
        1.3533528323661270e-01f, 6.0653065971263342e-01f, 1.0f,
        6.0653065971263342e-01f, 1.3533528323661270e-01f,
        1.1108996538242306e-02f, 3.3546262790251185e-04f };

    const int blk   = blockIdx.x;
    const int ch    = blk / BPC;        // 0..23 (0..11 pred, 12..23 target)
    const int chunk = blk % BPC;
    const float* src = (ch < NCH) ? (pred + (size_t)ch * HW)
                                  : (target + (size_t)(ch - NCH) * HW);

    // row-major lane-private columns: bank = lane%32 for every tap row,
    // conflict-free (2-way) independent of pixel data. No atomics.
    __shared__ float h[NW][PADBINS][64];   // 36864 B
    __shared__ float part[NW][BINS];

    const int wv   = threadIdx.x >> 6;
    const int lane = threadIdx.x & 63;

    // zero h: 9216 dwords = 2304 float4 / 128 thr = 18 each (exact)
    {
        float4* hz = (float4*)&h[0][0][0];
        #pragma unroll
        for (int t = 0; t < NW * PADBINS * 64 / 4 / THREADS; ++t)
            hz[threadIdx.x + t * THREADS] = make_float4(0.f, 0.f, 0.f, 0.f);
    }
    __syncthreads();

    // 512 float4 per block; thread t loads f4[t + k*128], k=0..3 (coalesced).
    const float4* src4 = (const float4*)(src + chunk * PIX_PER_BLOCK);
    float4 a = src4[threadIdx.x];
    float4 b = src4[threadIdx.x + THREADS];
    float4 c = src4[threadIdx.x + 2 * THREADS];
    float4 d = src4[threadIdx.x + 3 * THREADS];
    float px[PPT] = {a.x, a.y, a.z, a.w, b.x, b.y, b.z, b.w,
                     c.x, c.y, c.z, c.w, d.x, d.y, d.z, d.w};

    const float L  = 1.4426950408889634f;    // log2(e)
    const float L2 = 0.7213475204444817f;    // log2(e)/2

    #pragma unroll
    for (int p = 0; p < PPT; ++p) {
        float xt = px[p] * 64.0f - 0.5f;       // bin-center units
        float fi = rintf(xt);
        fi = fminf(fmaxf(fi, 0.0f), 63.0f);    // defensive clamp
        float f  = xt - fi;                    // [-0.5, 0.5]
        int   i  = (int)fi;                    // nearest bin -> rows i..i+8
        float P  = fast_exp2(-L2 * f * f - (float)R * L * f);
        float B  = fast_exp2(L * f);

        // batched RMW: 9 reads (one vaddr, offset:t*256) -> 9 fma -> 9 writes
        float v[WIN];
        #pragma unroll
        for (int t = 0; t < WIN; ++t) v[t] = h[wv][i + t][lane];
        #pragma unroll
        for (int t = 0; t < WIN; ++t) { v[t] = fmaf(P, CK[t], v[t]); P *= B; }
        #pragma unroll
        for (int t = 0; t < WIN; ++t) h[wv][i + t][lane] = v[t];
    }

    __syncthreads();

    // Per-wave column reduce: lane j sums 64 lane-columns at row j+R.
    // bank = ((j+R)*64 + j+cc) % 32 = (j+cc)%32: 2-way alias, free.
    {
        const int j = lane;
        float s = 0.0f;
        #pragma unroll
        for (int cc = 0; cc < 64; ++cc)
            s += h[wv][R + j][(j + cc) & 63];
        part[wv][j] = s;
    }
    __syncthreads();
    if (threadIdx.x < BINS) {
        const int j = threadIdx.x;
        part_out[blk * BINS + j] = part[0][j] + part[1][j];  // plain store
    }
}

__global__ __launch_bounds__(NCH * 64) void final_kernel(
        const float* __restrict__ part, float* __restrict__ out) {
    const int w    = threadIdx.x >> 6;   // 0..11 -> (b,c) channel
    const int lane = threadIdx.x & 63;   // bin

    // sum the 32 chunk-partials for pred and target (coalesced per c).
    float ph = 0.0f, th = 0.0f;
    #pragma unroll 8
    for (int c = 0; c < BPC; ++c) {
        ph += part[(w * BPC + c) * BINS + lane];
        th += part[((NCH + w) * BPC + c) * BINS + lane];
    }

    // inclusive scan over bins (wave64 shfl_up)
    float ps = ph, ts = th;
    #pragma unroll
    for (int d = 1; d < 64; d <<= 1) {
        float a = __shfl_up(ps, d, 64);
        float b = __shfl_up(ts, d, 64);
        if (lane >= d) { ps += a; ts += b; }
    }
    float ptot = __shfl(ps, 63, 64);
    float ttot = __shfl(ts, 63, 64);
    float pc = ps / (ptot + 1e-8f);
    float tc = ts / (ttot + 1e-8f);
    float dv = fabsf(pc - tc);

    // wave reduce
    #pragma unroll
    for (int k = 32; k >= 1; k >>= 1) dv += __shfl_xor(dv, k, 64);

    __shared__ float warr[NCH];
    if (lane == 0) warr[w] = dv;
    __syncthreads();
    if (threadIdx.x == 0) {
        float s = 0.0f;
        #pragma unroll
        for (int i = 0; i < NCH; ++i) s += warr[i];
        out[0] = s / (float)(NCH * BINS);
    }
}

extern "C" void kernel_launch(void* const* d_in, const int* in_sizes, int n_in,
                              void* d_out, int out_size, void* d_ws, size_t ws_size,
                              hipStream_t stream) {
    const float* pred   = (const float*)d_in[0];
    const float* target = (const float*)d_in[1];
    float* part = (float*)d_ws;          // 768*64 floats = 196 KB partials
    float* out  = (float*)d_out;

    hist_kernel<<<dim3(2 * NCH * BPC), dim3(THREADS), 0, stream>>>(
        pred, target, part);
    // PROBE: final launched 4x (idempotent). (total - 64.4)/3 = final + bnd.
    // Revert to single launch after this round.
    final_kernel<<<dim3(1), dim3(NCH * 64), 0, stream>>>(part, out);
    final_kernel<<<dim3(1), dim3(NCH * 64), 0, stream>>>(part, out);
    final_kernel<<<dim3(1), dim3(NCH * 64), 0, stream>>>(part, out);
    final_kernel<<<dim3(1), dim3(NCH * 64), 0, stream>>>(part, out);
}

// Round 15
// 63.947 us; speedup vs baseline: 1.1782x; 1.1782x over previous
//
#include <hip/hip_runtime.h>

// ColorHistogramLoss: soft histogram (Gaussian kernel, 64 bins) over
// pred/target (4,3,256,256) fp32, normalized, cumsum, mean |cdf diff|.
//
// v14 == v6/v11 (empirical optimum, 64.4us) — FINAL. Probes v12/v13
//   completed the time ledger; all terms measured:
//     fill (harness d_ws poison): 41.0us @ 82% HBM peak (untouchable)
//     hist + boundary:             5.2us (v12) — LDS-issue floor
//     final + boundary:            3.6us (v13) — single-CU BW model
//     fixed overhead:            ~14.6us — graph/sync envelope; every
//       removal attempt regressed: grid.sync fusion (v7 +130us),
//       fence-storm waiter (v9 +30), coherent RMW-poll waiter (v10 +12),
//       4 blk/CU occupancy (v8 +3.6).
//   Key mechanism results this session:
//   - LDS atomicAdd ~200cy/op, contention-INDEPENDENT (v2==v3=137us);
//     plain ds RMW on lane-private columns is the fix (v4: 65.4).
//   - Row-major h[wave][bin][lane]: bank = lane%32 — DATA-INDEPENDENT
//     conflict-free scatter. Transposed/b64-merged layouts (v5) have
//     data-dependent bank clumping: regressed.
//   - Truncated Gaussian R=4 (9 taps) + ratio recurrence: 2 exp2/pixel,
//     zero transcendentals per tap; absmax 0.0 throughout.
//
// Structure:
//   hist_kernel : 768 blocks x 128 thr (3 blocks/CU); h[2][72][64]
//                 row-major lane-private, batched read->fma->write RMW,
//                 staggered column reduce, partial store to d_ws
//   final_kernel: 1 block x 768 thr (12 waves); sum 32 chunk partials
//                 (coalesced), wave scan -> cdf -> |diff| -> mean

#define BINS 64
#define NCH 12            // B*C = 4*3
#define HW 65536          // 256*256
#define BPC 32            // pixel-chunks (blocks) per channel-image
#define PIX_PER_BLOCK (HW / BPC)              // 2048
#define THREADS 128
#define PPT (PIX_PER_BLOCK / THREADS)         // 16 pixels per thread
#define R 4               // Gaussian support radius (edge weight e^-8)
#define WIN (2 * R + 1)   // 9 taps
#define PADBINS (BINS + 2 * R)   // 72 rows: row = bin + R, bins -4..67
#define NW (THREADS / 64) // 2 waves

__device__ __forceinline__ float fast_exp2(float x) {
#if __has_builtin(__builtin_amdgcn_exp2f)
    return __builtin_amdgcn_exp2f(x);   // v_exp_f32
#else
    return exp2f(x);
#endif
}

// weight for bin i-R+t (t=0..8): exp(-(f-(t-R))^2/2) = CK[t] * P_t,
//   P_0 = exp(-f^2/2 - R*f)  (one exp2)    B = exp(f)  (one exp2)
//   P_{t+1} = P_t * B ;  CK[t] = exp(-(t-R)^2/2)  (compile-time)
// P_t = exp(-f^2/2 + (t-R)f) in [e^-2.125, e^2] — tiny fp32 range.
__global__ __launch_bounds__(THREADS) void hist_kernel(
        const float* __restrict__ pred,
        const float* __restrict__ target,
        float* __restrict__ part_out) {
    constexpr float CK[WIN] = {
        3.3546262790251185e-04f, 1.1108996538242306e-02f,
        1.3533528323661270e-01f, 6.0653065971263342e-01f, 1.0f,
        6.0653065971263342e-01f, 1.3533528323661270e-01f,
        1.1108996538242306e-02f, 3.3546262790251185e-04f };

    const int blk   = blockIdx.x;
    const int ch    = blk / BPC;        // 0..23 (0..11 pred, 12..23 target)
    const int chunk = blk % BPC;
    const float* src = (ch < NCH) ? (pred + (size_t)ch * HW)
                                  : (target + (size_t)(ch - NCH) * HW);

    // row-major lane-private columns: bank = lane%32 for every tap row,
    // conflict-free (2-way) independent of pixel data. No atomics.
    __shared__ float h[NW][PADBINS][64];   // 36864 B
    __shared__ float part[NW][BINS];

    const int wv   = threadIdx.x >> 6;
    const int lane = threadIdx.x & 63;

    // zero h: 9216 dwords = 2304 float4 / 128 thr = 18 each (exact)
    {
        float4* hz = (float4*)&h[0][0][0];
        #pragma unroll
        for (int t = 0; t < NW * PADBINS * 64 / 4 / THREADS; ++t)
            hz[threadIdx.x + t * THREADS] = make_float4(0.f, 0.f, 0.f, 0.f);
    }
    __syncthreads();

    // 512 float4 per block; thread t loads f4[t + k*128], k=0..3 (coalesced).
    const float4* src4 = (const float4*)(src + chunk * PIX_PER_BLOCK);
    float4 a = src4[threadIdx.x];
    float4 b = src4[threadIdx.x + THREADS];
    float4 c = src4[threadIdx.x + 2 * THREADS];
    float4 d = src4[threadIdx.x + 3 * THREADS];
    float px[PPT] = {a.x, a.y, a.z, a.w, b.x, b.y, b.z, b.w,
                     c.x, c.y, c.z, c.w, d.x, d.y, d.z, d.w};

    const float L  = 1.4426950408889634f;    // log2(e)
    const float L2 = 0.7213475204444817f;    // log2(e)/2

    #pragma unroll
    for (int p = 0; p < PPT; ++p) {
        float xt = px[p] * 64.0f - 0.5f;       // bin-center units
        float fi = rintf(xt);
        fi = fminf(fmaxf(fi, 0.0f), 63.0f);    // defensive clamp
        float f  = xt - fi;                    // [-0.5, 0.5]
        int   i  = (int)fi;                    // nearest bin -> rows i..i+8
        float P  = fast_exp2(-L2 * f * f - (float)R * L * f);
        float B  = fast_exp2(L * f);

        // batched RMW: 9 reads (one vaddr, offset:t*256) -> 9 fma -> 9 writes
        float v[WIN];
        #pragma unroll
        for (int t = 0; t < WIN; ++t) v[t] = h[wv][i + t][lane];
        #pragma unroll
        for (int t = 0; t < WIN; ++t) { v[t] = fmaf(P, CK[t], v[t]); P *= B; }
        #pragma unroll
        for (int t = 0; t < WIN; ++t) h[wv][i + t][lane] = v[t];
    }

    __syncthreads();

    // Per-wave column reduce: lane j sums 64 lane-columns at row j+R.
    // bank = ((j+R)*64 + j+cc) % 32 = (j+cc)%32: 2-way alias, free.
    {
        const int j = lane;
        float s = 0.0f;
        #pragma unroll
        for (int cc = 0; cc < 64; ++cc)
            s += h[wv][R + j][(j + cc) & 63];
        part[wv][j] = s;
    }
    __syncthreads();
    if (threadIdx.x < BINS) {
        const int j = threadIdx.x;
        part_out[blk * BINS + j] = part[0][j] + part[1][j];  // plain store
    }
}

__global__ __launch_bounds__(NCH * 64) void final_kernel(
        const float* __restrict__ part, float* __restrict__ out) {
    const int w    = threadIdx.x >> 6;   // 0..11 -> (b,c) channel
    const int lane = threadIdx.x & 63;   // bin

    // sum the 32 chunk-partials for pred and target (coalesced per c).
    float ph = 0.0f, th = 0.0f;
    #pragma unroll 8
    for (int c = 0; c < BPC; ++c) {
        ph += part[(w * BPC + c) * BINS + lane];
        th += part[((NCH + w) * BPC + c) * BINS + lane];
    }

    // inclusive scan over bins (wave64 shfl_up)
    float ps = ph, ts = th;
    #pragma unroll
    for (int d = 1; d < 64; d <<= 1) {
        float a = __shfl_up(ps, d, 64);
        float b = __shfl_up(ts, d, 64);
        if (lane >= d) { ps += a; ts += b; }
    }
    float ptot = __shfl(ps, 63, 64);
    float ttot = __shfl(ts, 63, 64);
    float pc = ps / (ptot + 1e-8f);
    float tc = ts / (ttot + 1e-8f);
    float dv = fabsf(pc - tc);

    // wave reduce
    #pragma unroll
    for (int k = 32; k >= 1; k >>= 1) dv += __shfl_xor(dv, k, 64);

    __shared__ float warr[NCH];
    if (lane == 0) warr[w] = dv;
    __syncthreads();
    if (threadIdx.x == 0) {
        float s = 0.0f;
        #pragma unroll
        for (int i = 0; i < NCH; ++i) s += warr[i];
        out[0] = s / (float)(NCH * BINS);
    }
}

extern "C" void kernel_launch(void* const* d_in, const int* in_sizes, int n_in,
                              void* d_out, int out_size, void* d_ws, size_t ws_size,
                              hipStream_t stream) {
    const float* pred   = (const float*)d_in[0];
    const float* target = (const float*)d_in[1];
    float* part = (float*)d_ws;          // 768*64 floats = 196 KB partials
    float* out  = (float*)d_out;

    hist_kernel<<<dim3(2 * NCH * BPC), dim3(THREADS), 0, stream>>>(
        pred, target, part);
    final_kernel<<<dim3(1), dim3(NCH * 64), 0, stream>>>(part, out);
}